// Round 1
// baseline (216.172 us; speedup 1.0000x reference)
//
#include <hip/hip_runtime.h>
#include <stdint.h>

// AM-softmax loss, fused on MI355X (gfx950) — round 9.
//
// vs round 8 (212 us; gemm 91 us at MfmaUtil 38.6%, HBM only 22% of peak;
// prep_all + finalize + gaps ~120 us):
//  * prep_w pass DELETED. gemm_lse reads W (fp32) directly and converts to
//    bf16 B-fragments in registers once per block — amortized over 4 bands
//    x 64 rows; the 8-consecutive-blocks-per-W-panel L2 mapping unchanged.
//    gemm had ~3x HBM headroom, so the fp32 W read (2x bytes vs packed bf16)
//    rides free under the compute; ~115 MB of reformat traffic disappears.
//  * prep shrinks to x-normalize only (512 blocks, ~2.3 MB, also zeroes
//    out[0]). Workspace no longer needs the 38.6 MB Wb buffer.
//  * gemm schedule, epilogue, finalize byte-identical to round 8 so the
//    gemm-dur delta cleanly isolates the direct-W cost.

constexpr int N  = 2048;
constexpr int D  = 192;               // K
constexpr int C  = 100000;
constexpr int KT = D / 32;            // 6 k-tiles of 32
constexpr int TILE = 512;             // elems per 16x32 fragment tile
constexpr int RT16 = C / 16;          // 6250 real 16-col tiles
constexpr int TPG = 12;               // 16-col tiles per block (4 waves x 3)
constexpr int CX = 523;               // col groups: 523*12 = 6276 tiles
constexpr int NT16 = CX * TPG;        // 6276 tiles = 100416 cols
constexpr float PHANTOM = (float)(NT16 * 16 - C);   // 416 exact ones
constexpr int BANDS = 4;              // 64-row bands per block
constexpr int RYB = N / (64 * BANDS); // 8 row groups
constexpr int BUF = 4 * KT * TILE;    // 12288 ushort = 24 KB per band buffer
constexpr int NXB = N / 4;            // 512 prep_x blocks

#define S_SCALE 30.0f
#define MARGIN  0.2f
#define S_LOG2E 43.2808512266689f     // 30 * log2(e)

using short8 = __attribute__((ext_vector_type(8))) short;   // 8 bf16 (4 VGPRs)
using f32x4  = __attribute__((ext_vector_type(4))) float;   // MFMA C/D

typedef __attribute__((address_space(1))) const void GV;
typedef __attribute__((address_space(3))) void LV;

__device__ inline unsigned short f2bf(float f) {  // fp32 -> bf16 RNE
  unsigned int u = __float_as_uint(f);
  u += 0x7fffu + ((u >> 16) & 1u);
  return (unsigned short)(u >> 16);
}

// packed fragment index (ushort units) for element (row r, k):
// tile (r>>4, k>>5), lane = (r&15) + ((k>>3)&3)*16, elem k&7.
__device__ inline int pack_idx(int r, int k) {
  return ((r >> 4) * KT + (k >> 5)) * TILE + (((k >> 3) & 3) * 16 + (r & 15)) * 8 + (k & 7);
}

// Sum across each 16-lane DPP row; result valid in all 16 lanes.
__device__ inline float row_sum16(float v) {
  int x;
  x = __float_as_int(v);
  v += __int_as_float(__builtin_amdgcn_update_dpp(0, x, 0x128, 0xF, 0xF, true)); // row_ror:8
  x = __float_as_int(v);
  v += __int_as_float(__builtin_amdgcn_update_dpp(0, x, 0x124, 0xF, 0xF, true)); // row_ror:4
  x = __float_as_int(v);
  v += __int_as_float(__builtin_amdgcn_update_dpp(0, x, 0x04E, 0xF, 0xF, true)); // quad_perm xor2
  x = __float_as_int(v);
  v += __int_as_float(__builtin_amdgcn_update_dpp(0, x, 0x0B1, 0xF, 0xF, true)); // quad_perm xor1
  return v;
}

// ---------------- prep: x-normalize + pack (+ zero out[0]) ----------------
__global__ __launch_bounds__(256) void prep_x(
    const float* __restrict__ x, unsigned short* __restrict__ xnb,
    float* __restrict__ out) {
  const int bid  = blockIdx.x;
  const int lane = threadIdx.x & 63;
  if (bid == 0 && threadIdx.x == 0) out[0] = 0.0f;   // for finalize atomics

  const int row = bid * 4 + (threadIdx.x >> 6);
  const float* xr = x + (size_t)row * D;
  float v0 = xr[lane], v1 = xr[lane + 64], v2 = xr[lane + 128];
  float ss = v0 * v0 + v1 * v1 + v2 * v2;
#pragma unroll
  for (int off = 32; off > 0; off >>= 1) ss += __shfl_xor(ss, off, 64);
  const float inv = rsqrtf(ss) * S_LOG2E;
  xnb[pack_idx(row, lane)]       = f2bf(v0 * inv);
  xnb[pack_idx(row, lane + 64)]  = f2bf(v1 * inv);
  xnb[pack_idx(row, lane + 128)] = f2bf(v2 * inv);
}

// ---------------- main fused GEMM + exp-rowsum ----------------------------
// 1-D grid CX*RYB; cx = bid>>3, ry = bid&7 (8 consecutive blocks share one
// W panel -> L2 reuse). Block = 4 waves; wave owns 48 cols (B in regs,
// loaded fp32 from W and converted to bf16 once per block). 4 bands of 64
// rows, A double-buffered (24 KB each), DMA prefetch one band ahead.
__global__ __launch_bounds__(256, 3) void gemm_lse(
    const unsigned short* __restrict__ xnb,  // packed [128 row-tiles][KT][512]
    const float* __restrict__ W,             // [C][D] fp32, row-major
    float* __restrict__ partial) {           // [CX][N]
  __shared__ alignas(16) unsigned short As[2 * BUF];   // 48 KB (double buffer)
  __shared__ alignas(16) float rs_lds[4][256];         // 4 KB

  const int tid = threadIdx.x;
  const int bid = blockIdx.x;
  const int cx = bid >> 3, ry = bid & 7;

  // ---- issue DMA for band 0 into buf 0 (24 KB, contiguous packed) ----
  {
    const unsigned short* slab = xnb + (size_t)(ry * BANDS) * BUF;
#pragma unroll
    for (int i = 0; i < 6; ++i) {            // 1536 x 16 B
      const int chunk = tid + i * 256;
      __builtin_amdgcn_global_load_lds(
          (GV*)((const char*)slab + (size_t)chunk * 16),
          (LV*)((char*)As + (size_t)chunk * 16), 16, 0, 0);
    }
  }

  const int lane = tid & 63, wave = tid >> 6;
  const int m = lane & 15, quad = lane >> 4;

  // ---- B fragments: fp32 W -> bf16 regs, once per block ----
  // Lane (m,quad) of tile t16 needs W[t16*16+m][ks*32 + quad*8 .. +8].
  // Same fragment values (f2bf RNE) the old prep_w produced.
  short8 breg[3][KT];
#pragma unroll
  for (int tc = 0; tc < 3; ++tc) {
    const int t16 = cx * TPG + wave * 3 + tc;
    if (t16 < RT16) {
      const float* src = W + (size_t)(t16 * 16 + m) * D + quad * 8;
#pragma unroll
      for (int ks = 0; ks < KT; ++ks) {
        const float4* s4 = (const float4*)(src + ks * 32);
        float4 f0 = s4[0], f1 = s4[1];
        short8 hv;
        hv[0] = (short)f2bf(f0.x); hv[1] = (short)f2bf(f0.y);
        hv[2] = (short)f2bf(f0.z); hv[3] = (short)f2bf(f0.w);
        hv[4] = (short)f2bf(f1.x); hv[5] = (short)f2bf(f1.y);
        hv[6] = (short)f2bf(f1.z); hv[7] = (short)f2bf(f1.w);
        breg[tc][ks] = hv;
      }
    } else {
      // phantom cols (>= C): zero fragment -> acc 0 -> exp2(0)=1, removed
      // via PHANTOM in finalize (unchanged from round 8).
      const short8 z = {0, 0, 0, 0, 0, 0, 0, 0};
#pragma unroll
      for (int ks = 0; ks < KT; ++ks) breg[tc][ks] = z;
    }
  }

  const f32x4 zero4 = {0.0f, 0.0f, 0.0f, 0.0f};

  for (int b = 0; b < BANDS; ++b) {
    __syncthreads();   // drains vmcnt: band b's DMA (issued a full band ago)

    // prefetch band b+1 into the other buffer BEFORE compute of band b
    if (b + 1 < BANDS) {
      const unsigned short* slab = xnb + (size_t)(ry * BANDS + b + 1) * BUF;
      char* dst = (char*)&As[((b + 1) & 1) * BUF];
#pragma unroll
      for (int i = 0; i < 6; ++i) {
        const int chunk = tid + i * 256;
        __builtin_amdgcn_global_load_lds(
            (GV*)((const char*)slab + (size_t)chunk * 16),
            (LV*)(dst + (size_t)chunk * 16), 16, 0, 0);
      }
    }

    const unsigned short* Ab = &As[(b & 1) * BUF];

    f32x4 acc[4][3];
#pragma unroll
    for (int a = 0; a < 4; ++a)
#pragma unroll
      for (int c = 0; c < 3; ++c) acc[a][c] = zero4;

#pragma unroll
    for (int ks = 0; ks < KT; ++ks) {
      short8 af[4];
#pragma unroll
      for (int tr = 0; tr < 4; ++tr)
        af[tr] = *(const short8*)(&Ab[(tr * KT + ks) * TILE + lane * 8]);
#pragma unroll
      for (int tr = 0; tr < 4; ++tr)
#pragma unroll
        for (int tc = 0; tc < 3; ++tc)
          acc[tr][tc] = __builtin_amdgcn_mfma_f32_16x16x32_bf16(
              af[tr], breg[tc][ks], acc[tr][tc], 0, 0, 0);
    }

    // ---- epilogue: exp2 (arg pre-scaled; phantom cols give exactly 1) ----
#pragma unroll
    for (int tr = 0; tr < 4; ++tr) {
      float rv0 = 0.f, rv1 = 0.f, rv2 = 0.f, rv3 = 0.f;
#pragma unroll
      for (int tc = 0; tc < 3; ++tc) {
        rv0 += __builtin_amdgcn_exp2f(acc[tr][tc][0]);
        rv1 += __builtin_amdgcn_exp2f(acc[tr][tc][1]);
        rv2 += __builtin_amdgcn_exp2f(acc[tr][tc][2]);
        rv3 += __builtin_amdgcn_exp2f(acc[tr][tc][3]);
      }
      rv0 = row_sum16(rv0);
      rv1 = row_sum16(rv1);
      rv2 = row_sum16(rv2);
      rv3 = row_sum16(rv3);
      if (m == 0) {
        float4 v = make_float4(rv0, rv1, rv2, rv3);
        *(float4*)(&rs_lds[wave][b * 64 + tr * 16 + quad * 4]) = v;
      }
    }
  }

  __syncthreads();  // all waves' rowsums in LDS
  if (tid < 256) {
    const float s = rs_lds[0][tid] + rs_lds[1][tid] + rs_lds[2][tid] + rs_lds[3][tid];
    partial[(size_t)cx * N + ry * 256 + tid] = s;   // coalesced, exclusive
  }
}

// ---------------- finalize: per-row loss + in-kernel mean reduce ----------
// One wave per row (4 rows/block): gather 523 partials + fp32 target logit in
// one shuffle reduction; block-sum -> one atomicAdd into out[0] (pre-zeroed).
__global__ __launch_bounds__(256) void finalize_rows(
    const float* __restrict__ x, const float* __restrict__ W,
    const int* __restrict__ label, const float* __restrict__ partial,
    float* __restrict__ out) {
  const int row  = blockIdx.x * 4 + (threadIdx.x >> 6);
  const int lane = threadIdx.x & 63;
  const float* xr = x + (size_t)row * D;
  float v0 = xr[lane], v1 = xr[lane + 64], v2 = xr[lane + 128];
  float ss = v0 * v0 + v1 * v1 + v2 * v2;
  const int lab = label[row];
  const float* wr = W + (size_t)lab * D;
  float d = v0 * wr[lane] + v1 * wr[lane + 64] + v2 * wr[lane + 128];
  float p = 0.0f;
  for (int s = lane; s < CX; s += 64) p += partial[(size_t)s * N + row];
#pragma unroll
  for (int off = 32; off > 0; off >>= 1) {
    ss += __shfl_xor(ss, off, 64);
    d  += __shfl_xor(d,  off, 64);
    p  += __shfl_xor(p,  off, 64);
  }
  __shared__ float part[4];
  if (lane == 0) {
    const float tgt   = d * rsqrtf(ss);
    const float numer = S_SCALE * (tgt - MARGIN);
    // remove phantom-ones, swap label column's exp for margin-adjusted exp
    const float se = p - PHANTOM - __expf(S_SCALE * tgt) + __expf(numer);
    part[threadIdx.x >> 6] = numer - logf(se);
  }
  __syncthreads();
  if (threadIdx.x == 0) {
    const float blocksum = part[0] + part[1] + part[2] + part[3];
    atomicAdd(out, -blocksum * (1.0f / (float)N));
  }
}

// ---------------- host ----------------------------------------------------
extern "C" void kernel_launch(void* const* d_in, const int* in_sizes, int n_in,
                              void* d_out, int out_size, void* d_ws, size_t ws_size,
                              hipStream_t stream) {
  const float* x     = (const float*)d_in[0];
  const float* W     = (const float*)d_in[1];
  const int*   label = (const int*)d_in[2];
  float*       out   = (float*)d_out;

  char* ws = (char*)d_ws;
  size_t off = 0;
  unsigned short* xnb = (unsigned short*)(ws + off); off += (size_t)N * D * 2;  // 768 KB
  float* partial = (float*)(ws + off); off += (size_t)CX * N * 4;               // 4.3 MB

  prep_x<<<NXB, 256, 0, stream>>>(x, xnb, out);

  gemm_lse<<<CX * RYB, 256, 0, stream>>>(xnb, W, partial);

  finalize_rows<<<N / 4, 256, 0, stream>>>(x, W, label, partial, out);
}

// Round 2
// 214.130 us; speedup vs baseline: 1.0095x; 1.0095x over previous
//
#include <hip/hip_runtime.h>
#include <stdint.h>

// AM-softmax loss, fused on MI355X (gfx950) — round 10.
//
// vs round 9 (216 us; gemm 124 us, MfmaUtil 26.7, FETCH 301 MB = 4x W):
//  * XCD-aware block remap (T1). Round 8/9's cx=bid>>3 put the 8 ry-blocks
//    sharing a W panel on 8 DIFFERENT XCDs (round-robin dispatch) -> zero
//    L2 sharing, 4x W over-fetch, memory-latency stalls on the MFMA pipe.
//    New map: xcd=bid&7, j=bid>>3, ry=j&7, cx=(j>>3)*8+xcd. All 8 ry-blocks
//    of a cx are adjacent in per-XCD dispatch order -> W panel fetched from
//    HBM once, 7/8 blocks hit L2 (~12 panels resident = 1.8 MB < 4 MB L2).
//    Grid padded to 528*8=4224; 40 blocks with cx>=523 exit immediately.
//  * Everything else byte-identical to round 9 (direct fp32 W read, no
//    prep_w pass) so the FETCH/MfmaUtil delta cleanly isolates the remap.

constexpr int N  = 2048;
constexpr int D  = 192;               // K
constexpr int C  = 100000;
constexpr int KT = D / 32;            // 6 k-tiles of 32
constexpr int TILE = 512;             // elems per 16x32 fragment tile
constexpr int RT16 = C / 16;          // 6250 real 16-col tiles
constexpr int TPG = 12;               // 16-col tiles per block (4 waves x 3)
constexpr int CX = 523;               // col groups: 523*12 = 6276 tiles
constexpr int NT16 = CX * TPG;        // 6276 tiles = 100416 cols
constexpr float PHANTOM = (float)(NT16 * 16 - C);   // 416 exact ones
constexpr int BANDS = 4;              // 64-row bands per block
constexpr int RYB = N / (64 * BANDS); // 8 row groups
constexpr int BUF = 4 * KT * TILE;    // 12288 ushort = 24 KB per band buffer
constexpr int NXB = N / 4;            // 512 prep_x blocks
constexpr int CXP = 528;              // cx padded to multiple of 8 (XCD remap)

#define S_SCALE 30.0f
#define MARGIN  0.2f
#define S_LOG2E 43.2808512266689f     // 30 * log2(e)

using short8 = __attribute__((ext_vector_type(8))) short;   // 8 bf16 (4 VGPRs)
using f32x4  = __attribute__((ext_vector_type(4))) float;   // MFMA C/D

typedef __attribute__((address_space(1))) const void GV;
typedef __attribute__((address_space(3))) void LV;

__device__ inline unsigned short f2bf(float f) {  // fp32 -> bf16 RNE
  unsigned int u = __float_as_uint(f);
  u += 0x7fffu + ((u >> 16) & 1u);
  return (unsigned short)(u >> 16);
}

// packed fragment index (ushort units) for element (row r, k):
// tile (r>>4, k>>5), lane = (r&15) + ((k>>3)&3)*16, elem k&7.
__device__ inline int pack_idx(int r, int k) {
  return ((r >> 4) * KT + (k >> 5)) * TILE + (((k >> 3) & 3) * 16 + (r & 15)) * 8 + (k & 7);
}

// Sum across each 16-lane DPP row; result valid in all 16 lanes.
__device__ inline float row_sum16(float v) {
  int x;
  x = __float_as_int(v);
  v += __int_as_float(__builtin_amdgcn_update_dpp(0, x, 0x128, 0xF, 0xF, true)); // row_ror:8
  x = __float_as_int(v);
  v += __int_as_float(__builtin_amdgcn_update_dpp(0, x, 0x124, 0xF, 0xF, true)); // row_ror:4
  x = __float_as_int(v);
  v += __int_as_float(__builtin_amdgcn_update_dpp(0, x, 0x04E, 0xF, 0xF, true)); // quad_perm xor2
  x = __float_as_int(v);
  v += __int_as_float(__builtin_amdgcn_update_dpp(0, x, 0x0B1, 0xF, 0xF, true)); // quad_perm xor1
  return v;
}

// ---------------- prep: x-normalize + pack (+ zero out[0]) ----------------
__global__ __launch_bounds__(256) void prep_x(
    const float* __restrict__ x, unsigned short* __restrict__ xnb,
    float* __restrict__ out) {
  const int bid  = blockIdx.x;
  const int lane = threadIdx.x & 63;
  if (bid == 0 && threadIdx.x == 0) out[0] = 0.0f;   // for finalize atomics

  const int row = bid * 4 + (threadIdx.x >> 6);
  const float* xr = x + (size_t)row * D;
  float v0 = xr[lane], v1 = xr[lane + 64], v2 = xr[lane + 128];
  float ss = v0 * v0 + v1 * v1 + v2 * v2;
#pragma unroll
  for (int off = 32; off > 0; off >>= 1) ss += __shfl_xor(ss, off, 64);
  const float inv = rsqrtf(ss) * S_LOG2E;
  xnb[pack_idx(row, lane)]       = f2bf(v0 * inv);
  xnb[pack_idx(row, lane + 64)]  = f2bf(v1 * inv);
  xnb[pack_idx(row, lane + 128)] = f2bf(v2 * inv);
}

// ---------------- main fused GEMM + exp-rowsum ----------------------------
// Grid CXP*RYB (4224). XCD-aware map: xcd=bid&7, j=bid>>3, ry=j&7,
// cx=(j>>3)*8+xcd -> the 8 ry-blocks of one cx are consecutive in per-XCD
// dispatch order (same L2). Block = 4 waves; wave owns 48 cols (B in regs,
// fp32 W -> bf16 convert once per block). 4 bands of 64 rows, A double-
// buffered (24 KB each), DMA prefetch one band ahead.
__global__ __launch_bounds__(256, 3) void gemm_lse(
    const unsigned short* __restrict__ xnb,  // packed [128 row-tiles][KT][512]
    const float* __restrict__ W,             // [C][D] fp32, row-major
    float* __restrict__ partial) {           // [CX][N]
  __shared__ alignas(16) unsigned short As[2 * BUF];   // 48 KB (double buffer)
  __shared__ alignas(16) float rs_lds[4][256];         // 4 KB

  const int tid = threadIdx.x;
  const int bid = blockIdx.x;
  const int xcd = bid & 7, j = bid >> 3;
  const int ry = j & 7;
  const int cx = (j >> 3) * 8 + xcd;
  if (cx >= CX) return;                     // 40 phantom blocks (pad to 528)

  // ---- issue DMA for band 0 into buf 0 (24 KB, contiguous packed) ----
  {
    const unsigned short* slab = xnb + (size_t)(ry * BANDS) * BUF;
#pragma unroll
    for (int i = 0; i < 6; ++i) {            // 1536 x 16 B
      const int chunk = tid + i * 256;
      __builtin_amdgcn_global_load_lds(
          (GV*)((const char*)slab + (size_t)chunk * 16),
          (LV*)((char*)As + (size_t)chunk * 16), 16, 0, 0);
    }
  }

  const int lane = tid & 63, wave = tid >> 6;
  const int m = lane & 15, quad = lane >> 4;

  // ---- B fragments: fp32 W -> bf16 regs, once per block ----
  // Lane (m,quad) of tile t16 needs W[t16*16+m][ks*32 + quad*8 .. +8].
  short8 breg[3][KT];
#pragma unroll
  for (int tc = 0; tc < 3; ++tc) {
    const int t16 = cx * TPG + wave * 3 + tc;
    if (t16 < RT16) {
      const float* src = W + (size_t)(t16 * 16 + m) * D + quad * 8;
#pragma unroll
      for (int ks = 0; ks < KT; ++ks) {
        const float4* s4 = (const float4*)(src + ks * 32);
        float4 f0 = s4[0], f1 = s4[1];
        short8 hv;
        hv[0] = (short)f2bf(f0.x); hv[1] = (short)f2bf(f0.y);
        hv[2] = (short)f2bf(f0.z); hv[3] = (short)f2bf(f0.w);
        hv[4] = (short)f2bf(f1.x); hv[5] = (short)f2bf(f1.y);
        hv[6] = (short)f2bf(f1.z); hv[7] = (short)f2bf(f1.w);
        breg[tc][ks] = hv;
      }
    } else {
      // phantom cols (>= C): zero fragment -> acc 0 -> exp2(0)=1, removed
      // via PHANTOM in finalize.
      const short8 z = {0, 0, 0, 0, 0, 0, 0, 0};
#pragma unroll
      for (int ks = 0; ks < KT; ++ks) breg[tc][ks] = z;
    }
  }

  const f32x4 zero4 = {0.0f, 0.0f, 0.0f, 0.0f};

  for (int b = 0; b < BANDS; ++b) {
    __syncthreads();   // drains vmcnt: band b's DMA (issued a full band ago)

    // prefetch band b+1 into the other buffer BEFORE compute of band b
    if (b + 1 < BANDS) {
      const unsigned short* slab = xnb + (size_t)(ry * BANDS + b + 1) * BUF;
      char* dst = (char*)&As[((b + 1) & 1) * BUF];
#pragma unroll
      for (int i = 0; i < 6; ++i) {
        const int chunk = tid + i * 256;
        __builtin_amdgcn_global_load_lds(
            (GV*)((const char*)slab + (size_t)chunk * 16),
            (LV*)(dst + (size_t)chunk * 16), 16, 0, 0);
      }
    }

    const unsigned short* Ab = &As[(b & 1) * BUF];

    f32x4 acc[4][3];
#pragma unroll
    for (int a = 0; a < 4; ++a)
#pragma unroll
      for (int c = 0; c < 3; ++c) acc[a][c] = zero4;

#pragma unroll
    for (int ks = 0; ks < KT; ++ks) {
      short8 af[4];
#pragma unroll
      for (int tr = 0; tr < 4; ++tr)
        af[tr] = *(const short8*)(&Ab[(tr * KT + ks) * TILE + lane * 8]);
#pragma unroll
      for (int tr = 0; tr < 4; ++tr)
#pragma unroll
        for (int tc = 0; tc < 3; ++tc)
          acc[tr][tc] = __builtin_amdgcn_mfma_f32_16x16x32_bf16(
              af[tr], breg[tc][ks], acc[tr][tc], 0, 0, 0);
    }

    // ---- epilogue: exp2 (arg pre-scaled; phantom cols give exactly 1) ----
#pragma unroll
    for (int tr = 0; tr < 4; ++tr) {
      float rv0 = 0.f, rv1 = 0.f, rv2 = 0.f, rv3 = 0.f;
#pragma unroll
      for (int tc = 0; tc < 3; ++tc) {
        rv0 += __builtin_amdgcn_exp2f(acc[tr][tc][0]);
        rv1 += __builtin_amdgcn_exp2f(acc[tr][tc][1]);
        rv2 += __builtin_amdgcn_exp2f(acc[tr][tc][2]);
        rv3 += __builtin_amdgcn_exp2f(acc[tr][tc][3]);
      }
      rv0 = row_sum16(rv0);
      rv1 = row_sum16(rv1);
      rv2 = row_sum16(rv2);
      rv3 = row_sum16(rv3);
      if (m == 0) {
        float4 v = make_float4(rv0, rv1, rv2, rv3);
        *(float4*)(&rs_lds[wave][b * 64 + tr * 16 + quad * 4]) = v;
      }
    }
  }

  __syncthreads();  // all waves' rowsums in LDS
  if (tid < 256) {
    const float s = rs_lds[0][tid] + rs_lds[1][tid] + rs_lds[2][tid] + rs_lds[3][tid];
    partial[(size_t)cx * N + ry * 256 + tid] = s;   // coalesced, exclusive
  }
}

// ---------------- finalize: per-row loss + in-kernel mean reduce ----------
// One wave per row (4 rows/block): gather 523 partials + fp32 target logit in
// one shuffle reduction; block-sum -> one atomicAdd into out[0] (pre-zeroed).
__global__ __launch_bounds__(256) void finalize_rows(
    const float* __restrict__ x, const float* __restrict__ W,
    const int* __restrict__ label, const float* __restrict__ partial,
    float* __restrict__ out) {
  const int row  = blockIdx.x * 4 + (threadIdx.x >> 6);
  const int lane = threadIdx.x & 63;
  const float* xr = x + (size_t)row * D;
  float v0 = xr[lane], v1 = xr[lane + 64], v2 = xr[lane + 128];
  float ss = v0 * v0 + v1 * v1 + v2 * v2;
  const int lab = label[row];
  const float* wr = W + (size_t)lab * D;
  float d = v0 * wr[lane] + v1 * wr[lane + 64] + v2 * wr[lane + 128];
  float p = 0.0f;
  for (int s = lane; s < CX; s += 64) p += partial[(size_t)s * N + row];
#pragma unroll
  for (int off = 32; off > 0; off >>= 1) {
    ss += __shfl_xor(ss, off, 64);
    d  += __shfl_xor(d,  off, 64);
    p  += __shfl_xor(p,  off, 64);
  }
  __shared__ float part[4];
  if (lane == 0) {
    const float tgt   = d * rsqrtf(ss);
    const float numer = S_SCALE * (tgt - MARGIN);
    // remove phantom-ones, swap label column's exp for margin-adjusted exp
    const float se = p - PHANTOM - __expf(S_SCALE * tgt) + __expf(numer);
    part[threadIdx.x >> 6] = numer - logf(se);
  }
  __syncthreads();
  if (threadIdx.x == 0) {
    const float blocksum = part[0] + part[1] + part[2] + part[3];
    atomicAdd(out, -blocksum * (1.0f / (float)N));
  }
}

// ---------------- host ----------------------------------------------------
extern "C" void kernel_launch(void* const* d_in, const int* in_sizes, int n_in,
                              void* d_out, int out_size, void* d_ws, size_t ws_size,
                              hipStream_t stream) {
  const float* x     = (const float*)d_in[0];
  const float* W     = (const float*)d_in[1];
  const int*   label = (const int*)d_in[2];
  float*       out   = (float*)d_out;

  char* ws = (char*)d_ws;
  size_t off = 0;
  unsigned short* xnb = (unsigned short*)(ws + off); off += (size_t)N * D * 2;  // 768 KB
  float* partial = (float*)(ws + off); off += (size_t)CX * N * 4;               // 4.3 MB

  prep_x<<<NXB, 256, 0, stream>>>(x, xnb, out);

  gemm_lse<<<CXP * RYB, 256, 0, stream>>>(xnb, W, partial);

  finalize_rows<<<N / 4, 256, 0, stream>>>(x, W, label, partial, out);
}